// Round 1
// baseline (1042.305 us; speedup 1.0000x reference)
//
#include <hip/hip_runtime.h>
#include <math.h>

#define BB 2
#define DD 8
#define NN 40
#define HH 128
#define HID 512
#define TILE 16

// hn[row][c] = sum_h max_d(node[b][d][i][h]) * W1n[h][c],  row = b*NN+i
__global__ __launch_bounds__(128) void hn_kernel(const float* __restrict__ node,
                                                 const float* __restrict__ W1n,
                                                 float* __restrict__ hn) {
    __shared__ float nf[HH];
    int row = blockIdx.x;          // b*NN + i
    int b = row / NN, i = row % NN;
    int t = threadIdx.x;           // 0..127
    float m = -INFINITY;
    #pragma unroll
    for (int d = 0; d < DD; ++d)
        m = fmaxf(m, node[((b*DD + d)*NN + i)*HH + t]);
    nf[t] = m;
    __syncthreads();
    float acc[4] = {0.f, 0.f, 0.f, 0.f};
    for (int h = 0; h < HH; ++h) {
        float nv = nf[h];
        #pragma unroll
        for (int q = 0; q < 4; ++q)
            acc[q] = fmaf(nv, W1n[h*HID + t + q*128], acc[q]);
    }
    #pragma unroll
    for (int q = 0; q < 4; ++q)
        hn[row*HID + t + q*128] = acc[q];
}

// hp[row][c] = sum_h max_d(pair[b][d][jk][h]) * W1p[h][c],  row = b*1600+jk
__global__ __launch_bounds__(128) void hp_kernel(const float* __restrict__ pair,
                                                 const float* __restrict__ W1p,
                                                 float* __restrict__ hp) {
    __shared__ float pf[HH];
    int row = blockIdx.x;              // b*1600 + jk
    int b = row / (NN*NN), jk = row % (NN*NN);
    int t = threadIdx.x;
    float m = -INFINITY;
    #pragma unroll
    for (int d = 0; d < DD; ++d)
        m = fmaxf(m, pair[((b*DD + d)*(NN*NN) + jk)*HH + t]);
    pf[t] = m;
    __syncthreads();
    float acc[4] = {0.f, 0.f, 0.f, 0.f};
    for (int h = 0; h < HH; ++h) {
        float pv = pf[h];
        #pragma unroll
        for (int q = 0; q < 4; ++q)
            acc[q] = fmaf(pv, W1p[h*HID + t + q*128], acc[q]);
    }
    #pragma unroll
    for (int q = 0; q < 4; ++q)
        hp[row*HID + t + q*128] = acc[q];
}

// One block = 16 output rows sharing hn[b,i]; rows are consecutive (j,k) pairs.
// h1 = relu(hn + hp + b1) staged in LDS; acc = h1 @ W2 + b2 (2 cols/thread);
// epilogue: v = relu(acc) @ W3 + b3 -> sigmoid(scale*v + bias).
__global__ __launch_bounds__(256, 4) void main_kernel(
        const float* __restrict__ hn, const float* __restrict__ hp,
        const float* __restrict__ b1, const float* __restrict__ W2,
        const float* __restrict__ b2, const float* __restrict__ W3,
        const float* __restrict__ b3, const float* __restrict__ scale,
        const float* __restrict__ bias, float* __restrict__ out) {
    __shared__ float h1[TILE*HID];     // 32 KiB
    __shared__ float red[TILE*4];
    int bid = blockIdx.x;              // 8000 = BB*NN*100
    int b   = bid / (NN*100);
    int rem = bid % (NN*100);
    int i   = rem / 100;
    int jk0 = (rem % 100) * TILE;
    int t = threadIdx.x;

    const float* hnrow  = hn + (b*NN + i)*HID;
    const float* hprows = hp + (b*NN*NN + jk0)*HID;

    for (int idx = t; idx < TILE*HID; idx += 256) {
        int r = idx >> 9, c = idx & 511;
        h1[idx] = fmaxf(hnrow[c] + hprows[r*HID + c] + b1[c], 0.0f);
    }
    __syncthreads();

    float bb0 = b2[t], bb1 = b2[t + 256];
    float acc0[TILE], acc1[TILE];
    #pragma unroll
    for (int r = 0; r < TILE; ++r) { acc0[r] = bb0; acc1[r] = bb1; }

    for (int k = 0; k < HID; k += 4) {
        float w0[4], w1[4];
        #pragma unroll
        for (int u = 0; u < 4; ++u) {
            w0[u] = W2[(k + u)*HID + t];
            w1[u] = W2[(k + u)*HID + t + 256];
        }
        #pragma unroll
        for (int r = 0; r < TILE; ++r) {
            float4 hv = *(const float4*)&h1[r*HID + k];
            acc0[r] = fmaf(hv.x, w0[0], acc0[r]);
            acc0[r] = fmaf(hv.y, w0[1], acc0[r]);
            acc0[r] = fmaf(hv.z, w0[2], acc0[r]);
            acc0[r] = fmaf(hv.w, w0[3], acc0[r]);
            acc1[r] = fmaf(hv.x, w1[0], acc1[r]);
            acc1[r] = fmaf(hv.y, w1[1], acc1[r]);
            acc1[r] = fmaf(hv.z, w1[2], acc1[r]);
            acc1[r] = fmaf(hv.w, w1[3], acc1[r]);
        }
    }

    float w3a = W3[t], w3b = W3[t + 256];
    int lane = t & 63, wid = t >> 6;
    #pragma unroll
    for (int r = 0; r < TILE; ++r) {
        float v = fmaxf(acc0[r], 0.f)*w3a + fmaxf(acc1[r], 0.f)*w3b;
        #pragma unroll
        for (int off = 32; off; off >>= 1) v += __shfl_down(v, off);
        if (lane == 0) red[r*4 + wid] = v;
    }
    __syncthreads();
    if (t < TILE) {
        float v = red[t*4] + red[t*4+1] + red[t*4+2] + red[t*4+3] + b3[0];
        float z = scale[0]*v + bias[0];
        out[(b*NN + i)*(NN*NN) + jk0 + t] = 1.0f / (1.0f + expf(-z));
    }
}

extern "C" void kernel_launch(void* const* d_in, const int* in_sizes, int n_in,
                              void* d_out, int out_size, void* d_ws, size_t ws_size,
                              hipStream_t stream) {
    const float* node  = (const float*)d_in[0];
    const float* pair  = (const float*)d_in[1];
    const float* W1n   = (const float*)d_in[2];
    const float* W1p   = (const float*)d_in[3];
    const float* b1    = (const float*)d_in[4];
    const float* W2    = (const float*)d_in[5];
    const float* b2    = (const float*)d_in[6];
    const float* W3    = (const float*)d_in[7];
    const float* b3    = (const float*)d_in[8];
    const float* scale = (const float*)d_in[9];
    const float* bias  = (const float*)d_in[10];
    float* out = (float*)d_out;

    float* hn = (float*)d_ws;                 // 80*512 floats
    float* hp = hn + BB*NN*HID;               // 3200*512 floats

    hipLaunchKernelGGL(hn_kernel, dim3(BB*NN), dim3(128), 0, stream, node, W1n, hn);
    hipLaunchKernelGGL(hp_kernel, dim3(BB*NN*NN), dim3(128), 0, stream, pair, W1p, hp);
    hipLaunchKernelGGL(main_kernel, dim3(BB*NN*100), dim3(256), 0, stream,
                       hn, hp, b1, W2, b2, W3, b3, scale, bias, out);
}

// Round 2
// 368.342 us; speedup vs baseline: 2.8297x; 2.8297x over previous
//
#include <hip/hip_runtime.h>
#include <math.h>

#define BB 2
#define DD 8
#define NN 40
#define HH 128
#define HID 512
#define MBLK 64

typedef __attribute__((ext_vector_type(8))) short short8;
typedef __attribute__((ext_vector_type(4))) float floatx4;

static __device__ __forceinline__ unsigned short f2bf(float x) {
    unsigned int b = __float_as_uint(x);
    b += 0x7fffu + ((b >> 16) & 1u);
    return (unsigned short)(b >> 16);
}

// hn[row][c] = sum_h max_d(node[b][d][i][h]) * W1n[h][c] ,  row = b*NN+i   (fp32)
__global__ __launch_bounds__(128) void hn_kernel(const float* __restrict__ node,
                                                 const float* __restrict__ W1n,
                                                 float* __restrict__ hn) {
    __shared__ float nf[HH];
    int row = blockIdx.x;
    int b = row / NN, i = row % NN;
    int t = threadIdx.x;
    float m = -INFINITY;
    #pragma unroll
    for (int d = 0; d < DD; ++d)
        m = fmaxf(m, node[((b*DD + d)*NN + i)*HH + t]);
    nf[t] = m;
    __syncthreads();
    float acc[4] = {0.f, 0.f, 0.f, 0.f};
    for (int h = 0; h < HH; ++h) {
        float nv = nf[h];
        #pragma unroll
        for (int q = 0; q < 4; ++q)
            acc[q] = fmaf(nv, W1n[h*HID + t + q*128], acc[q]);
    }
    #pragma unroll
    for (int q = 0; q < 4; ++q)
        hn[row*HID + t + q*128] = acc[q];
}

// hp[row][c] = sum_h max_d(pair[b][d][jk][h]) * W1p[h][c],  row = b*1600+jk  (fp32)
__global__ __launch_bounds__(128) void hp_kernel(const float* __restrict__ pair,
                                                 const float* __restrict__ W1p,
                                                 float* __restrict__ hp) {
    __shared__ float pf[HH];
    int row = blockIdx.x;
    int b = row / (NN*NN), jk = row % (NN*NN);
    int t = threadIdx.x;
    float m = -INFINITY;
    #pragma unroll
    for (int d = 0; d < DD; ++d)
        m = fmaxf(m, pair[((b*DD + d)*(NN*NN) + jk)*HH + t]);
    pf[t] = m;
    __syncthreads();
    float acc[4] = {0.f, 0.f, 0.f, 0.f};
    for (int h = 0; h < HH; ++h) {
        float pv = pf[h];
        #pragma unroll
        for (int q = 0; q < 4; ++q)
            acc[q] = fmaf(pv, W1p[h*HID + t + q*128], acc[q]);
    }
    #pragma unroll
    for (int q = 0; q < 4; ++q)
        hp[row*HID + t + q*128] = acc[q];
}

// W2T[n][k] = bf16(W2[k][n])  — LDS-tiled transpose, 256 blocks of 32x8
__global__ __launch_bounds__(256) void w2t_kernel(const float* __restrict__ W2,
                                                  unsigned short* __restrict__ W2T) {
    __shared__ float tile[32][33];
    int bx = blockIdx.x & 15;      // k-tile
    int by = blockIdx.x >> 4;      // n-tile
    int k0 = bx * 32, n0 = by * 32;
    int tx = threadIdx.x & 31, ty = threadIdx.x >> 5;   // 32 x 8
    #pragma unroll
    for (int r = 0; r < 4; ++r)
        tile[ty + r*8][tx] = W2[(k0 + ty + r*8)*HID + n0 + tx];
    __syncthreads();
    #pragma unroll
    for (int r = 0; r < 4; ++r)
        W2T[(n0 + ty + r*8)*HID + k0 + tx] = f2bf(tile[tx][ty + r*8]);
}

// One block = 64 rows (fixed b,i ; 64 consecutive jk). 8 waves as 2M x 4N,
// wave tile 32x128, mfma_f32_16x16x32_bf16. h1 in LDS bf16 (XOR-swizzled).
__global__ __launch_bounds__(512, 4) void main_kernel(
        const float* __restrict__ hn, const float* __restrict__ hp,
        const float* __restrict__ b1, const unsigned short* __restrict__ w2t,
        const float* __restrict__ b2, const float* __restrict__ W3,
        const float* __restrict__ b3, const float* __restrict__ scale,
        const float* __restrict__ bias, float* __restrict__ out) {
    __shared__ unsigned short h1s[MBLK * HID];   // 64 KiB, swizzled bf16
    __shared__ float hnb[HID];                   // hn row + b1
    __shared__ float red[4][MBLK];

    const int bid = blockIdx.x;                  // 2000 = BB*NN*25
    const int b   = bid / (NN*25);
    const int rem = bid % (NN*25);
    const int i   = rem / 25;
    const int jk0 = (rem % 25) * MBLK;
    const int t   = threadIdx.x;

    hnb[t] = hn[(b*NN + i)*HID + t] + b1[t];
    __syncthreads();

    // h1 tile: relu(hnb + hp) -> bf16 -> swizzled LDS
    const float* hpbase = hp + (size_t)(b*NN*NN + jk0) * HID;
    for (int e = t; e < MBLK * (HID/4); e += 512) {
        int row = e >> 7, kq = e & 127;
        float4 hp4 = *(const float4*)(hpbase + row*HID + kq*4);
        ushort4 u;
        u.x = f2bf(fmaxf(hnb[kq*4+0] + hp4.x, 0.f));
        u.y = f2bf(fmaxf(hnb[kq*4+1] + hp4.y, 0.f));
        u.z = f2bf(fmaxf(hnb[kq*4+2] + hp4.z, 0.f));
        u.w = f2bf(fmaxf(hnb[kq*4+3] + hp4.w, 0.f));
        int off = ((row << 10) + (kq << 3)) ^ ((row & 7) << 4);
        *(ushort4*)((char*)h1s + off) = u;
    }
    __syncthreads();

    const int l  = t & 63;
    const int w  = t >> 6;
    const int mi = w >> 2;           // 0..1
    const int ni = w & 3;            // 0..3
    const int lr = l & 15;
    const int lg = l >> 4;

    floatx4 acc[2][8];
    #pragma unroll
    for (int tm = 0; tm < 2; ++tm)
        #pragma unroll
        for (int tn = 0; tn < 8; ++tn)
            acc[tm][tn] = (floatx4){0.f, 0.f, 0.f, 0.f};

    // per-lane W2T base: row (ni*128 + lr), k offset lg*8
    const unsigned short* w2l = w2t + (size_t)(ni*128 + lr) * HID + lg*8;
    const char* h1c = (const char*)h1s;
    const int arow0 = mi*32 + lr;
    const int abase0 = (arow0 << 10) + (lg << 4);
    const int abase1 = ((arow0 + 16) << 10) + (lg << 4);
    const int swz = (arow0 & 7) << 4;            // same for arow0+16

    #pragma unroll 2
    for (int k0 = 0; k0 < HID; k0 += 32) {
        int kb = k0 << 1;
        short8 a0 = *(const short8*)(h1c + ((abase0 + kb) ^ swz));
        short8 a1 = *(const short8*)(h1c + ((abase1 + kb) ^ swz));
        #pragma unroll
        for (int tn = 0; tn < 8; ++tn) {
            short8 bf = *(const short8*)(w2l + tn*16*HID + k0);
            acc[0][tn] = __builtin_amdgcn_mfma_f32_16x16x32_bf16(a0, bf, acc[0][tn], 0, 0, 0);
            acc[1][tn] = __builtin_amdgcn_mfma_f32_16x16x32_bf16(a1, bf, acc[1][tn], 0, 0, 0);
        }
    }

    // epilogue: v = relu(acc + b2) @ W3 ; row-reduce; sigmoid
    float b2v[8], w3v[8];
    #pragma unroll
    for (int tn = 0; tn < 8; ++tn) {
        int col = ni*128 + tn*16 + lr;
        b2v[tn] = b2[col];
        w3v[tn] = W3[col];
    }
    #pragma unroll
    for (int tm = 0; tm < 2; ++tm) {
        #pragma unroll
        for (int r = 0; r < 4; ++r) {
            float s = 0.f;
            #pragma unroll
            for (int tn = 0; tn < 8; ++tn)
                s += fmaxf(acc[tm][tn][r] + b2v[tn], 0.f) * w3v[tn];
            s += __shfl_xor(s, 1);
            s += __shfl_xor(s, 2);
            s += __shfl_xor(s, 4);
            s += __shfl_xor(s, 8);
            if (lr == 0) red[ni][mi*32 + tm*16 + lg*4 + r] = s;
        }
    }
    __syncthreads();
    if (t < MBLK) {
        float v = red[0][t] + red[1][t] + red[2][t] + red[3][t] + b3[0];
        float z = scale[0] * v + bias[0];
        out[(size_t)(b*NN + i) * (NN*NN) + jk0 + t] = 1.0f / (1.0f + expf(-z));
    }
}

extern "C" void kernel_launch(void* const* d_in, const int* in_sizes, int n_in,
                              void* d_out, int out_size, void* d_ws, size_t ws_size,
                              hipStream_t stream) {
    const float* node  = (const float*)d_in[0];
    const float* pair  = (const float*)d_in[1];
    const float* W1n   = (const float*)d_in[2];
    const float* W1p   = (const float*)d_in[3];
    const float* b1    = (const float*)d_in[4];
    const float* W2    = (const float*)d_in[5];
    const float* b2    = (const float*)d_in[6];
    const float* W3    = (const float*)d_in[7];
    const float* b3    = (const float*)d_in[8];
    const float* scale = (const float*)d_in[9];
    const float* bias  = (const float*)d_in[10];
    float* out = (float*)d_out;

    float* hn = (float*)d_ws;                                  // 80*512 f32
    float* hp = hn + BB*NN*HID;                                // 3200*512 f32
    unsigned short* w2tp = (unsigned short*)(hp + BB*NN*NN*HID); // 512*512 bf16

    hipLaunchKernelGGL(hn_kernel, dim3(BB*NN), dim3(128), 0, stream, node, W1n, hn);
    hipLaunchKernelGGL(hp_kernel, dim3(BB*NN*NN), dim3(128), 0, stream, pair, W1p, hp);
    hipLaunchKernelGGL(w2t_kernel, dim3(256), dim3(256), 0, stream, W2, w2tp);
    hipLaunchKernelGGL(main_kernel, dim3(BB*NN*25), dim3(512), 0, stream,
                       hn, hp, b1, w2tp, b2, W3, b3, scale, bias, out);
}

// Round 3
// 195.646 us; speedup vs baseline: 5.3275x; 1.8827x over previous
//
#include <hip/hip_runtime.h>
#include <math.h>

#define BB 2
#define DD 8
#define NN 40
#define HH 128
#define HID 512
#define NJK 1600            // NN*NN
#define MROW 64000          // NN*NJK rows per batch
#define MBLK 128            // rows per main block
#define NBLK 500            // MROW / MBLK

typedef __attribute__((ext_vector_type(8))) short short8;
typedef __attribute__((ext_vector_type(4))) float floatx4;

static __device__ __forceinline__ unsigned short f2bf(float x) {
    unsigned int b = __float_as_uint(x);
    b += 0x7fffu + ((b >> 16) & 1u);
    return (unsigned short)(b >> 16);
}

// Fused prep:
//  bid in [0,1600)        : hp rows bid*2 + (t>=128)   (3200 rows, fp32)
//  bid in [1600,1640)     : hnb rows (bid-1600)*2+(t>=128) = hn@W1n + b1 (80 rows)
//  bid in [1640,1768)     : w2f — W2 packed bf16 in MFMA-fragment order:
//                           frag f = cf*16+ks holds 64 lanes x short8,
//                           lane l: n = cf*16+(l&15), k = ks*32+(l>>4)*8 .. +7
__global__ __launch_bounds__(256) void prep_kernel(
        const float* __restrict__ node, const float* __restrict__ pair,
        const float* __restrict__ W1n, const float* __restrict__ W1p,
        const float* __restrict__ b1, const float* __restrict__ W2,
        float* __restrict__ hp, float* __restrict__ hnb,
        unsigned short* __restrict__ w2f) {
    __shared__ float sf[2][HH];
    const int bid = blockIdx.x;
    const int t = threadIdx.x;

    if (bid < NJK) {                                   // ---- hp ----
        int half = t >> 7, tt = t & 127;
        int row = bid*2 + half;                        // 0..3199
        int b = row / NJK, jk = row % NJK;
        float m = -INFINITY;
        #pragma unroll
        for (int d = 0; d < DD; ++d)
            m = fmaxf(m, pair[((size_t)((b*DD + d)*NJK + jk))*HH + tt]);
        sf[half][tt] = m;
        __syncthreads();
        float acc[4] = {0.f, 0.f, 0.f, 0.f};
        for (int h = 0; h < HH; ++h) {
            float v = sf[half][h];
            #pragma unroll
            for (int q = 0; q < 4; ++q)
                acc[q] = fmaf(v, W1p[h*HID + tt + q*128], acc[q]);
        }
        #pragma unroll
        for (int q = 0; q < 4; ++q)
            hp[(size_t)row*HID + tt + q*128] = acc[q];
    } else if (bid < NJK + 40) {                       // ---- hnb ----
        int half = t >> 7, tt = t & 127;
        int row = (bid - NJK)*2 + half;                // 0..79
        int b = row / NN, i = row % NN;
        float m = -INFINITY;
        #pragma unroll
        for (int d = 0; d < DD; ++d)
            m = fmaxf(m, node[((size_t)((b*DD + d)*NN + i))*HH + tt]);
        sf[half][tt] = m;
        __syncthreads();
        float acc[4] = {0.f, 0.f, 0.f, 0.f};
        for (int h = 0; h < HH; ++h) {
            float v = sf[half][h];
            #pragma unroll
            for (int q = 0; q < 4; ++q)
                acc[q] = fmaf(v, W1n[h*HID + tt + q*128], acc[q]);
        }
        #pragma unroll
        for (int q = 0; q < 4; ++q)
            hnb[(size_t)row*HID + tt + q*128] = acc[q] + b1[tt + q*128];
    } else {                                           // ---- w2f ----
        int tid = (bid - (NJK + 40))*256 + t;          // 0..32767
        int frag = tid >> 6;                           // 0..511 = cf*16+ks
        int lane = tid & 63;
        int n  = (frag >> 4)*16 + (lane & 15);
        int k0 = (frag & 15)*32 + (lane >> 4)*8;
        short8 u;
        #pragma unroll
        for (int kk = 0; kk < 8; ++kk)
            u[kk] = (short)f2bf(W2[(size_t)(k0 + kk)*HID + n]);
        *(short8*)(w2f + (size_t)tid*8) = u;
    }
}

// Main: block = 128 rows x 512 cols. 8 waves, wave w owns cols [w*64,(w+1)*64),
// all 128 rows: acc[8][4]. h1 staged ONCE in 128KB swizzled LDS bf16; k-loop
// has no barriers; B prefetched one k-step ahead from fragment-packed w2f (L2).
__global__ __launch_bounds__(512, 2) void main_kernel(
        const float* __restrict__ hp, const float* __restrict__ hnb,
        const unsigned short* __restrict__ w2f,
        const float* __restrict__ b2, const float* __restrict__ W3,
        const float* __restrict__ b3, const float* __restrict__ scale,
        const float* __restrict__ bias, float* __restrict__ out) {
    __shared__ unsigned short h1s[MBLK * HID];         // 128 KiB, swizzled
    const int bid = blockIdx.x;                        // 0..999
    const int b   = bid / NBLK;
    const int m0  = (bid % NBLK) * MBLK;
    const int t   = threadIdx.x;
    char* h1c = (char*)h1s;

    // ---- stage h1 = relu(hnb[i] + hp[jk]) as bf16, swizzled ----
    const float* hpb  = hp  + (size_t)b * NJK * HID;
    const float* hnbb = hnb + (size_t)b * NN  * HID;
    #pragma unroll
    for (int it = 0; it < 16; ++it) {
        int g   = it*512 + t;                          // 0..8191
        int row = g >> 6, k8 = g & 63;                 // row, 8-elem group
        int ig  = m0 + row;
        int i   = ig / NJK;
        int jk  = ig - i*NJK;
        const float* hr = hpb  + (size_t)jk*HID + k8*8;
        const float* nr = hnbb + (size_t)i *HID + k8*8;
        float4 p0 = *(const float4*)hr, p1 = *(const float4*)(hr + 4);
        float4 n0 = *(const float4*)nr, n1 = *(const float4*)(nr + 4);
        short8 u;
        u[0] = (short)f2bf(fmaxf(p0.x + n0.x, 0.f));
        u[1] = (short)f2bf(fmaxf(p0.y + n0.y, 0.f));
        u[2] = (short)f2bf(fmaxf(p0.z + n0.z, 0.f));
        u[3] = (short)f2bf(fmaxf(p0.w + n0.w, 0.f));
        u[4] = (short)f2bf(fmaxf(p1.x + n1.x, 0.f));
        u[5] = (short)f2bf(fmaxf(p1.y + n1.y, 0.f));
        u[6] = (short)f2bf(fmaxf(p1.z + n1.z, 0.f));
        u[7] = (short)f2bf(fmaxf(p1.w + n1.w, 0.f));
        int off = ((row << 10) + (k8 << 4)) ^ ((row & 7) << 4);
        *(short8*)(h1c + off) = u;
    }
    __syncthreads();

    const int w  = t >> 6, l = t & 63;
    const int lr = l & 15, lg = l >> 4;
    const int swz = (lr & 7) << 4;

    floatx4 acc[8][4];
    #pragma unroll
    for (int mi = 0; mi < 8; ++mi)
        #pragma unroll
        for (int tn = 0; tn < 4; ++tn)
            acc[mi][tn] = (floatx4){0.f, 0.f, 0.f, 0.f};

    // B fragments: wave w -> cf = w*4+tn; frag (cf,ks) is 512 contiguous shorts
    const unsigned short* bbase = w2f + (size_t)w*32768 + l*8;

    short8 bcur[4];
    #pragma unroll
    for (int tn = 0; tn < 4; ++tn)
        bcur[tn] = *(const short8*)(bbase + (tn*16 + 0)*512);

    #pragma unroll 2
    for (int ks = 0; ks < 16; ++ks) {
        short8 bnxt[4];
        int ksn = (ks + 1) & 15;
        #pragma unroll
        for (int tn = 0; tn < 4; ++tn)
            bnxt[tn] = *(const short8*)(bbase + (tn*16 + ksn)*512);
        #pragma unroll
        for (int mi = 0; mi < 8; ++mi) {
            int aoff = ((((mi*16 + lr) << 10) + (ks << 6) + (lg << 4))) ^ swz;
            short8 a = *(const short8*)(h1c + aoff);
            #pragma unroll
            for (int tn = 0; tn < 4; ++tn)
                acc[mi][tn] = __builtin_amdgcn_mfma_f32_16x16x32_bf16(a, bcur[tn], acc[mi][tn], 0, 0, 0);
        }
        #pragma unroll
        for (int tn = 0; tn < 4; ++tn) bcur[tn] = bnxt[tn];
    }

    // ---- epilogue: v = relu(acc+b2)@W3, reduce, sigmoid ----
    __syncthreads();                      // all h1 reads done; reuse LDS as red
    float* red = (float*)h1s;             // [8][128]
    float b2v[4], w3v[4];
    #pragma unroll
    for (int tn = 0; tn < 4; ++tn) {
        int col = w*64 + tn*16 + lr;
        b2v[tn] = b2[col];
        w3v[tn] = W3[col];
    }
    #pragma unroll
    for (int mi = 0; mi < 8; ++mi) {
        #pragma unroll
        for (int r = 0; r < 4; ++r) {
            float s = 0.f;
            #pragma unroll
            for (int tn = 0; tn < 4; ++tn)
                s += fmaxf(acc[mi][tn][r] + b2v[tn], 0.f) * w3v[tn];
            s += __shfl_xor(s, 1);
            s += __shfl_xor(s, 2);
            s += __shfl_xor(s, 4);
            s += __shfl_xor(s, 8);
            if (lr == 0) red[w*128 + mi*16 + lg*4 + r] = s;
        }
    }
    __syncthreads();
    if (t < MBLK) {
        float v = b3[0];
        #pragma unroll
        for (int ww = 0; ww < 8; ++ww) v += red[ww*128 + t];
        float z = scale[0]*v + bias[0];
        out[(size_t)b*MROW + m0 + t] = 1.0f / (1.0f + expf(-z));
    }
}

extern "C" void kernel_launch(void* const* d_in, const int* in_sizes, int n_in,
                              void* d_out, int out_size, void* d_ws, size_t ws_size,
                              hipStream_t stream) {
    const float* node  = (const float*)d_in[0];
    const float* pair  = (const float*)d_in[1];
    const float* W1n   = (const float*)d_in[2];
    const float* W1p   = (const float*)d_in[3];
    const float* b1    = (const float*)d_in[4];
    const float* W2    = (const float*)d_in[5];
    const float* b2    = (const float*)d_in[6];
    const float* W3    = (const float*)d_in[7];
    const float* b3    = (const float*)d_in[8];
    const float* scale = (const float*)d_in[9];
    const float* bias  = (const float*)d_in[10];
    float* out = (float*)d_out;

    float* hp = (float*)d_ws;                                   // 3200*512 f32
    float* hnb = hp + (size_t)BB*NJK*HID;                       // 80*512 f32
    unsigned short* w2f = (unsigned short*)(hnb + BB*NN*HID);   // 512*512 bf16

    hipLaunchKernelGGL(prep_kernel, dim3(NJK + 40 + 128), dim3(256), 0, stream,
                       node, pair, W1n, W1p, b1, W2, hp, hnb, w2f);
    hipLaunchKernelGGL(main_kernel, dim3(BB*NBLK), dim3(512), 0, stream,
                       hp, hnb, w2f, b2, W3, b3, scale, bias, out);
}

// Round 4
// 184.769 us; speedup vs baseline: 5.6411x; 1.0589x over previous
//
#include <hip/hip_runtime.h>
#include <math.h>

#define BB 2
#define DD 8
#define NN 40
#define HH 128
#define HID 512
#define NJK 1600            // NN*NN
#define MROW 64000          // NN*NJK rows per batch

typedef __attribute__((ext_vector_type(8))) short short8;
typedef __attribute__((ext_vector_type(4))) float floatx4;

static __device__ __forceinline__ unsigned short f2bf(float x) {
    unsigned int b = __float_as_uint(x);
    b += 0x7fffu + ((b >> 16) & 1u);
    return (unsigned short)(b >> 16);
}

// Fused prep, 333 blocks x 256:
//  bid [0,200)   : hp rows bid*16..+15   (3200 rows, fp32, 16 rows share W1p pass)
//  bid [200,205) : hnb rows (bid-200)*16..+15  (80 rows, = max@W1n + b1)
//  bid [205,333) : w2f  — W2 packed bf16 in MFMA-fragment order:
//                  frag f = cf*16+ks at w2f+f*512; lane l: n=cf*16+(l&15),
//                  k = ks*32+(l>>4)*8 .. +7
__global__ __launch_bounds__(256) void prep_kernel(
        const float* __restrict__ node, const float* __restrict__ pair,
        const float* __restrict__ W1n, const float* __restrict__ W1p,
        const float* __restrict__ b1, const float* __restrict__ W2,
        float* __restrict__ hp, float* __restrict__ hnb,
        unsigned short* __restrict__ w2f) {
    const int bid = blockIdx.x;
    const int t = threadIdx.x;

    if (bid < 200) {                                   // ---- hp ----
        __shared__ float pf[16][HH];
        const int rowbase = bid * 16;
        for (int e = t; e < 16*HH; e += 256) {
            int r16 = e >> 7, c = e & 127;
            int grow = rowbase + r16;
            int b = grow / NJK, jk = grow - b*NJK;
            float m = -INFINITY;
            #pragma unroll
            for (int d = 0; d < DD; ++d)
                m = fmaxf(m, pair[((size_t)((b*DD + d)*NJK + jk))*HH + c]);
            pf[r16][c] = m;
        }
        __syncthreads();
        const int rg = t >> 7, c4 = (t & 127) * 4;
        float4 acc[8];
        #pragma unroll
        for (int r = 0; r < 8; ++r) acc[r] = make_float4(0.f,0.f,0.f,0.f);
        #pragma unroll 4
        for (int h = 0; h < HH; ++h) {
            float4 wv = *(const float4*)&W1p[h*HID + c4];
            #pragma unroll
            for (int r = 0; r < 8; ++r) {
                float pv = pf[rg*8 + r][h];
                acc[r].x = fmaf(pv, wv.x, acc[r].x);
                acc[r].y = fmaf(pv, wv.y, acc[r].y);
                acc[r].z = fmaf(pv, wv.z, acc[r].z);
                acc[r].w = fmaf(pv, wv.w, acc[r].w);
            }
        }
        #pragma unroll
        for (int r = 0; r < 8; ++r)
            *(float4*)&hp[(size_t)(rowbase + rg*8 + r)*HID + c4] = acc[r];
    } else if (bid < 205) {                            // ---- hnb ----
        __shared__ float nf[16][HH];
        const int rowbase = (bid - 200) * 16;
        for (int e = t; e < 16*HH; e += 256) {
            int r16 = e >> 7, c = e & 127;
            int grow = rowbase + r16;
            int b = grow / NN, i = grow - b*NN;
            float m = -INFINITY;
            #pragma unroll
            for (int d = 0; d < DD; ++d)
                m = fmaxf(m, node[((size_t)((b*DD + d)*NN + i))*HH + c]);
            nf[r16][c] = m;
        }
        __syncthreads();
        const int rg = t >> 7, c4 = (t & 127) * 4;
        float4 acc[8];
        #pragma unroll
        for (int r = 0; r < 8; ++r) acc[r] = make_float4(0.f,0.f,0.f,0.f);
        #pragma unroll 4
        for (int h = 0; h < HH; ++h) {
            float4 wv = *(const float4*)&W1n[h*HID + c4];
            #pragma unroll
            for (int r = 0; r < 8; ++r) {
                float nv = nf[rg*8 + r][h];
                acc[r].x = fmaf(nv, wv.x, acc[r].x);
                acc[r].y = fmaf(nv, wv.y, acc[r].y);
                acc[r].z = fmaf(nv, wv.z, acc[r].z);
                acc[r].w = fmaf(nv, wv.w, acc[r].w);
            }
        }
        float4 b1v = *(const float4*)&b1[c4];
        #pragma unroll
        for (int r = 0; r < 8; ++r) {
            float4 o = make_float4(acc[r].x + b1v.x, acc[r].y + b1v.y,
                                   acc[r].z + b1v.z, acc[r].w + b1v.w);
            *(float4*)&hnb[(size_t)(rowbase + rg*8 + r)*HID + c4] = o;
        }
    } else {                                           // ---- w2f ----
        int tid = (bid - 205)*256 + t;                 // 0..32767
        int frag = tid >> 6;
        int lane = tid & 63;
        int n  = (frag >> 4)*16 + (lane & 15);
        int k0 = (frag & 15)*32 + (lane >> 4)*8;
        short8 u;
        #pragma unroll
        for (int kk = 0; kk < 8; ++kk)
            u[kk] = (short)f2bf(W2[(size_t)(k0 + kk)*HID + n]);
        *(short8*)(w2f + (size_t)tid*8) = u;
    }
}

// Main: 1000 blocks x 1024 threads. Tile = 8 i's x 16 jk = 128 rows x 512 cols.
// 16 waves = 2 row-groups x 8 col-waves; wave = 64 rows x 64 cols, acc[4][4].
// h1 (128x512 bf16, XOR-swizzled) staged once in 128KB LDS; barrier-free k-loop;
// B from fragment-packed w2f (L2/L1). 4 waves/SIMD for latency hiding.
__global__ __launch_bounds__(1024, 4) void main_kernel(
        const float* __restrict__ hp, const float* __restrict__ hnb,
        const unsigned short* __restrict__ w2f,
        const float* __restrict__ b2, const float* __restrict__ W3,
        const float* __restrict__ b3, const float* __restrict__ scale,
        const float* __restrict__ bias, float* __restrict__ out) {
    __shared__ unsigned short h1s[128 * HID];          // 128 KiB, swizzled
    __shared__ float hnbs[8 * HID];                    // 16 KiB
    __shared__ float red[8][128];                      // 4 KiB

    const int bid  = blockIdx.x;                       // 0..999
    const int bid8 = (bid & 7)*125 + (bid >> 3);       // bijective XCD chunk swizzle
    const int b    = bid8 / 500;
    const int rr_  = bid8 % 500;
    const int i0   = (rr_ / 100) * 8;
    const int jk0  = (rr_ % 100) * 16;
    const int t    = threadIdx.x;
    char* h1c = (char*)h1s;

    // ---- stage hnb rows i0..i0+7 (b1 already folded in) ----
    {
        int row = t >> 7, c4 = (t & 127) * 4;
        *(float4*)&hnbs[row*HID + c4] =
            *(const float4*)&hnb[(size_t)(b*NN + i0 + row)*HID + c4];
    }
    __syncthreads();

    // ---- stage h1 = relu(hnbs[il] + hp[jk0+jl]) as bf16, swizzled ----
    const float* hpb = hp + ((size_t)b*NJK + jk0)*HID;
    #pragma unroll
    for (int it = 0; it < 8; ++it) {
        int g   = it*1024 + t;                         // 0..8191
        int row = g >> 6, k8 = g & 63;
        int il  = row >> 4, jl = row & 15;
        const float* hr = hpb + (size_t)jl*HID + k8*8;
        const float* nr = hnbs + il*HID + k8*8;
        float4 p0 = *(const float4*)hr, p1 = *(const float4*)(hr + 4);
        float4 n0 = *(const float4*)nr, n1 = *(const float4*)(nr + 4);
        short8 u;
        u[0] = (short)f2bf(fmaxf(p0.x + n0.x, 0.f));
        u[1] = (short)f2bf(fmaxf(p0.y + n0.y, 0.f));
        u[2] = (short)f2bf(fmaxf(p0.z + n0.z, 0.f));
        u[3] = (short)f2bf(fmaxf(p0.w + n0.w, 0.f));
        u[4] = (short)f2bf(fmaxf(p1.x + n1.x, 0.f));
        u[5] = (short)f2bf(fmaxf(p1.y + n1.y, 0.f));
        u[6] = (short)f2bf(fmaxf(p1.z + n1.z, 0.f));
        u[7] = (short)f2bf(fmaxf(p1.w + n1.w, 0.f));
        int off = ((row << 10) + (k8 << 4)) ^ ((row & 7) << 4);
        *(short8*)(h1c + off) = u;
    }
    __syncthreads();

    const int w  = t >> 6, l = t & 63;
    const int rg = w >> 3, cw = w & 7;                 // row-group, col-wave
    const int lr = l & 15, lg = l >> 4;

    floatx4 acc[4][4];
    #pragma unroll
    for (int mi = 0; mi < 4; ++mi)
        #pragma unroll
        for (int tn = 0; tn < 4; ++tn)
            acc[mi][tn] = (floatx4){0.f, 0.f, 0.f, 0.f};

    const unsigned short* bbase = w2f + (size_t)cw*32768 + l*8;
    const int rowb = rg*64 + lr;
    const int swz  = (lr & 7) << 4;

    #pragma unroll 1
    for (int ks = 0; ks < 16; ++ks) {
        short8 bf[4], av[4];
        #pragma unroll
        for (int tn = 0; tn < 4; ++tn)
            bf[tn] = *(const short8*)(bbase + ((tn*16 + ks) << 9));
        #pragma unroll
        for (int mi = 0; mi < 4; ++mi) {
            int aoff = (((rowb + mi*16) << 10) + (ks << 6) + (lg << 4)) ^ swz;
            av[mi] = *(const short8*)(h1c + aoff);
        }
        #pragma unroll
        for (int mi = 0; mi < 4; ++mi)
            #pragma unroll
            for (int tn = 0; tn < 4; ++tn)
                acc[mi][tn] = __builtin_amdgcn_mfma_f32_16x16x32_bf16(av[mi], bf[tn], acc[mi][tn], 0, 0, 0);
    }

    // ---- epilogue: v = relu(acc+b2)@W3, reduce over cols, sigmoid ----
    float b2v[4], w3v[4];
    #pragma unroll
    for (int tn = 0; tn < 4; ++tn) {
        int col = cw*64 + tn*16 + lr;
        b2v[tn] = b2[col];
        w3v[tn] = W3[col];
    }
    #pragma unroll
    for (int mi = 0; mi < 4; ++mi) {
        #pragma unroll
        for (int q = 0; q < 4; ++q) {
            float s = 0.f;
            #pragma unroll
            for (int tn = 0; tn < 4; ++tn)
                s += fmaxf(acc[mi][tn][q] + b2v[tn], 0.f) * w3v[tn];
            s += __shfl_xor(s, 1);
            s += __shfl_xor(s, 2);
            s += __shfl_xor(s, 4);
            s += __shfl_xor(s, 8);
            if (lr == 0) red[cw][rg*64 + mi*16 + lg*4 + q] = s;
        }
    }
    __syncthreads();
    if (t < 128) {
        float v = b3[0];
        #pragma unroll
        for (int c = 0; c < 8; ++c) v += red[c][t];
        float z = scale[0]*v + bias[0];
        int il = t >> 4, jl = t & 15;
        out[(size_t)b*MROW + (size_t)(i0 + il)*NJK + jk0 + jl] =
            1.0f / (1.0f + expf(-z));
    }
}

extern "C" void kernel_launch(void* const* d_in, const int* in_sizes, int n_in,
                              void* d_out, int out_size, void* d_ws, size_t ws_size,
                              hipStream_t stream) {
    const float* node  = (const float*)d_in[0];
    const float* pair  = (const float*)d_in[1];
    const float* W1n   = (const float*)d_in[2];
    const float* W1p   = (const float*)d_in[3];
    const float* b1    = (const float*)d_in[4];
    const float* W2    = (const float*)d_in[5];
    const float* b2    = (const float*)d_in[6];
    const float* W3    = (const float*)d_in[7];
    const float* b3    = (const float*)d_in[8];
    const float* scale = (const float*)d_in[9];
    const float* bias  = (const float*)d_in[10];
    float* out = (float*)d_out;

    float* hp = (float*)d_ws;                                   // 3200*512 f32
    float* hnb = hp + (size_t)BB*NJK*HID;                       // 80*512 f32
    unsigned short* w2f = (unsigned short*)(hnb + BB*NN*HID);   // 512*512 bf16

    hipLaunchKernelGGL(prep_kernel, dim3(333), dim3(256), 0, stream,
                       node, pair, W1n, W1p, b1, W2, hp, hnb, w2f);
    hipLaunchKernelGGL(main_kernel, dim3(1000), dim3(1024), 0, stream,
                       hp, hnb, w2f, b2, W3, b3, scale, bias, out);
}

// Round 5
// 179.472 us; speedup vs baseline: 5.8076x; 1.0295x over previous
//
#include <hip/hip_runtime.h>
#include <math.h>

#define BB 2
#define DD 8
#define NN 40
#define HH 128
#define HID 512
#define NJK 1600            // NN*NN
#define MROW 64000          // NN*NJK rows per batch

typedef __attribute__((ext_vector_type(8))) short short8;
typedef __attribute__((ext_vector_type(4))) float floatx4;

static __device__ __forceinline__ unsigned short f2bf(float x) {
    unsigned int b = __float_as_uint(x);
    b += 0x7fffu + ((b >> 16) & 1u);
    return (unsigned short)(b >> 16);
}

// Fused prep, 426 blocks x 256:
//  bid [0,400)   : hp rows bid*8..+7      (max_d(pair) @ W1p, fp32)
//  bid [400,410) : hnb rows (bid-400)*8..+7  (max_d(node) @ W1n + b1)
//  bid [410,426) : w2f — W2 k-slice ks=bid-410 packed bf16 in MFMA-frag order:
//                  frag f = cf*16+ks at w2f+f*512; lane l: n=cf*16+(l&15),
//                  k = ks*32+(l>>4)*8 .. +7
__global__ __launch_bounds__(256) void prep_kernel(
        const float* __restrict__ node, const float* __restrict__ pair,
        const float* __restrict__ W1n, const float* __restrict__ W1p,
        const float* __restrict__ b1, const float* __restrict__ W2,
        float* __restrict__ hp, float* __restrict__ hnb,
        unsigned short* __restrict__ w2f) {
    __shared__ float smem[32 * 513];                   // 65.7 KB, unioned
    const int bid = blockIdx.x;
    const int t = threadIdx.x;

    if (bid < 400) {                                   // ---- hp ----
        float (*pf)[HH] = (float (*)[HH])smem;         // [8][128]
        const int rowbase = bid * 8;
        #pragma unroll
        for (int e = t; e < 8*HH; e += 256) {
            int r8 = e >> 7, c = e & 127;
            int grow = rowbase + r8;
            int b = grow / NJK, jk = grow - b*NJK;
            float m = -INFINITY;
            #pragma unroll
            for (int d = 0; d < DD; ++d)
                m = fmaxf(m, pair[((size_t)((b*DD + d)*NJK + jk))*HH + c]);
            pf[r8][c] = m;
        }
        __syncthreads();
        const int rg = t >> 7, c4 = (t & 127) * 4;
        float4 acc[4];
        #pragma unroll
        for (int r = 0; r < 4; ++r) acc[r] = make_float4(0.f,0.f,0.f,0.f);
        #pragma unroll 4
        for (int h = 0; h < HH; ++h) {
            float4 wv = *(const float4*)&W1p[h*HID + c4];
            #pragma unroll
            for (int r = 0; r < 4; ++r) {
                float pv = pf[rg*4 + r][h];
                acc[r].x = fmaf(pv, wv.x, acc[r].x);
                acc[r].y = fmaf(pv, wv.y, acc[r].y);
                acc[r].z = fmaf(pv, wv.z, acc[r].z);
                acc[r].w = fmaf(pv, wv.w, acc[r].w);
            }
        }
        #pragma unroll
        for (int r = 0; r < 4; ++r)
            *(float4*)&hp[(size_t)(rowbase + rg*4 + r)*HID + c4] = acc[r];
    } else if (bid < 410) {                            // ---- hnb ----
        float (*nf)[HH] = (float (*)[HH])smem;         // [8][128]
        const int rowbase = (bid - 400) * 8;
        #pragma unroll
        for (int e = t; e < 8*HH; e += 256) {
            int r8 = e >> 7, c = e & 127;
            int grow = rowbase + r8;
            int b = grow / NN, i = grow - b*NN;
            float m = -INFINITY;
            #pragma unroll
            for (int d = 0; d < DD; ++d)
                m = fmaxf(m, node[((size_t)((b*DD + d)*NN + i))*HH + c]);
            nf[r8][c] = m;
        }
        __syncthreads();
        const int rg = t >> 7, c4 = (t & 127) * 4;
        float4 acc[4];
        #pragma unroll
        for (int r = 0; r < 4; ++r) acc[r] = make_float4(0.f,0.f,0.f,0.f);
        #pragma unroll 4
        for (int h = 0; h < HH; ++h) {
            float4 wv = *(const float4*)&W1n[h*HID + c4];
            #pragma unroll
            for (int r = 0; r < 4; ++r) {
                float nv = nf[rg*4 + r][h];
                acc[r].x = fmaf(nv, wv.x, acc[r].x);
                acc[r].y = fmaf(nv, wv.y, acc[r].y);
                acc[r].z = fmaf(nv, wv.z, acc[r].z);
                acc[r].w = fmaf(nv, wv.w, acc[r].w);
            }
        }
        float4 b1v = *(const float4*)&b1[c4];
        #pragma unroll
        for (int r = 0; r < 4; ++r) {
            float4 o = make_float4(acc[r].x + b1v.x, acc[r].y + b1v.y,
                                   acc[r].z + b1v.z, acc[r].w + b1v.w);
            *(float4*)&hnb[(size_t)(rowbase + rg*4 + r)*HID + c4] = o;
        }
    } else {                                           // ---- w2f ----
        const int ks = bid - 410;                      // 0..15, k rows ks*32..+31
        // stage 32x512 f32 coalesced, pad-1 (bank = (r+c)%32 -> <=2-way)
        for (int e = t; e < 32*HID; e += 256) {
            int r = e >> 9, c = e & 511;
            smem[r*513 + c] = W2[(size_t)(ks*32 + r)*HID + c];
        }
        __syncthreads();
        const int w = t >> 6, l = t & 63;
        const int lr = l & 15, lg = l >> 4;
        #pragma unroll
        for (int f = 0; f < 8; ++f) {
            int cf = w*8 + f;
            short8 u;
            #pragma unroll
            for (int kk = 0; kk < 8; ++kk)
                u[kk] = (short)f2bf(smem[(lg*8 + kk)*513 + cf*16 + lr]);
            *(short8*)(w2f + (size_t)(cf*16 + ks)*512 + l*8) = u;
        }
    }
}

// Main: 1000 blocks x 512 threads. Tile = 8 i's x 16 jk = 128 rows x 512 cols.
// 8 waves, wave w = ALL 128 rows x cols [w*64,(w+1)*64): acc[8][4].
// Every B frag feeds 8 MFMAs (128 rows) -> B-L2 = 32 B/cy/CU (< 56 budget).
// h1 (128x512 bf16, XOR-swizzled) staged once in 128KB LDS; barrier-free k-loop.
__global__ __launch_bounds__(512, 2) void main_kernel(
        const float* __restrict__ hp, const float* __restrict__ hnb,
        const unsigned short* __restrict__ w2f,
        const float* __restrict__ b2, const float* __restrict__ W3,
        const float* __restrict__ b3, const float* __restrict__ scale,
        const float* __restrict__ bias, float* __restrict__ out) {
    __shared__ unsigned short h1s[128 * HID];          // 128 KiB, swizzled
    __shared__ float red[8][128];                      // 4 KiB

    const int bid  = blockIdx.x;                       // 0..999
    const int bid8 = (bid & 7)*125 + (bid >> 3);       // bijective XCD swizzle
    const int b    = bid8 / 500;
    const int rr_  = bid8 % 500;
    const int i0   = (rr_ / 100) * 8;
    const int jk0  = (rr_ % 100) * 16;
    const int t    = threadIdx.x;
    char* h1c = (char*)h1s;

    // ---- stage h1 = relu(hnb[i] + hp[jk]) as bf16, swizzled ----
    // per wave per iter: one hp row + one hnb row, both coalesced (L1-hot)
    const float* hpb  = hp  + ((size_t)b*NJK + jk0)*HID;
    const float* hnbb = hnb + ((size_t)(b*NN + i0))*HID;
    #pragma unroll 4
    for (int it = 0; it < 16; ++it) {
        int g   = it*512 + t;                          // 0..8191
        int row = g >> 6, k8 = g & 63;
        int il  = row >> 4, jl = row & 15;
        const float* hr = hpb  + (size_t)jl*HID + k8*8;
        const float* nr = hnbb + (size_t)il*HID + k8*8;
        float4 p0 = *(const float4*)hr, p1 = *(const float4*)(hr + 4);
        float4 n0 = *(const float4*)nr, n1 = *(const float4*)(nr + 4);
        short8 u;
        u[0] = (short)f2bf(fmaxf(p0.x + n0.x, 0.f));
        u[1] = (short)f2bf(fmaxf(p0.y + n0.y, 0.f));
        u[2] = (short)f2bf(fmaxf(p0.z + n0.z, 0.f));
        u[3] = (short)f2bf(fmaxf(p0.w + n0.w, 0.f));
        u[4] = (short)f2bf(fmaxf(p1.x + n1.x, 0.f));
        u[5] = (short)f2bf(fmaxf(p1.y + n1.y, 0.f));
        u[6] = (short)f2bf(fmaxf(p1.z + n1.z, 0.f));
        u[7] = (short)f2bf(fmaxf(p1.w + n1.w, 0.f));
        int off = ((row << 10) + (k8 << 4)) ^ ((row & 7) << 4);
        *(short8*)(h1c + off) = u;
    }
    __syncthreads();

    const int w  = t >> 6, l = t & 63;
    const int lr = l & 15, lg = l >> 4;
    const int swz = (lr & 7) << 4;

    floatx4 acc[8][4];
    #pragma unroll
    for (int mi = 0; mi < 8; ++mi)
        #pragma unroll
        for (int tn = 0; tn < 4; ++tn)
            acc[mi][tn] = (floatx4){0.f, 0.f, 0.f, 0.f};

    // B frags: wave w -> cf = w*4+tn; frag (cf,ks) = 512 contiguous shorts
    const unsigned short* bbase = w2f + (size_t)w*32768 + l*8;

    short8 bcur[4];
    #pragma unroll
    for (int tn = 0; tn < 4; ++tn)
        bcur[tn] = *(const short8*)(bbase + ((tn*16 + 0) << 9));

    #pragma unroll 1
    for (int ks = 0; ks < 16; ++ks) {
        short8 bnxt[4];
        int ksn = (ks + 1) & 15;
        #pragma unroll
        for (int tn = 0; tn < 4; ++tn)
            bnxt[tn] = *(const short8*)(bbase + ((tn*16 + ksn) << 9));
        short8 av[8];
        #pragma unroll
        for (int mi = 0; mi < 8; ++mi) {
            int aoff = (((mi*16 + lr) << 10) + (ks << 6) + (lg << 4)) ^ swz;
            av[mi] = *(const short8*)(h1c + aoff);
        }
        #pragma unroll
        for (int mi = 0; mi < 8; ++mi)
            #pragma unroll
            for (int tn = 0; tn < 4; ++tn)
                acc[mi][tn] = __builtin_amdgcn_mfma_f32_16x16x32_bf16(av[mi], bcur[tn], acc[mi][tn], 0, 0, 0);
        #pragma unroll
        for (int tn = 0; tn < 4; ++tn) bcur[tn] = bnxt[tn];
    }

    // ---- epilogue: v = relu(acc+b2)@W3, reduce over col-waves, sigmoid ----
    float b2v[4], w3v[4];
    #pragma unroll
    for (int tn = 0; tn < 4; ++tn) {
        int col = w*64 + tn*16 + lr;
        b2v[tn] = b2[col];
        w3v[tn] = W3[col];
    }
    #pragma unroll
    for (int mi = 0; mi < 8; ++mi) {
        #pragma unroll
        for (int q = 0; q < 4; ++q) {
            float s = 0.f;
            #pragma unroll
            for (int tn = 0; tn < 4; ++tn)
                s += fmaxf(acc[mi][tn][q] + b2v[tn], 0.f) * w3v[tn];
            s += __shfl_xor(s, 1);
            s += __shfl_xor(s, 2);
            s += __shfl_xor(s, 4);
            s += __shfl_xor(s, 8);
            if (lr == 0) red[w][mi*16 + lg*4 + q] = s;
        }
    }
    __syncthreads();
    if (t < 128) {
        float v = b3[0];
        #pragma unroll
        for (int c = 0; c < 8; ++c) v += red[c][t];
        float z = scale[0]*v + bias[0];
        int il = t >> 4, jl = t & 15;
        out[(size_t)b*MROW + (size_t)(i0 + il)*NJK + jk0 + jl] =
            1.0f / (1.0f + expf(-z));
    }
}

extern "C" void kernel_launch(void* const* d_in, const int* in_sizes, int n_in,
                              void* d_out, int out_size, void* d_ws, size_t ws_size,
                              hipStream_t stream) {
    const float* node  = (const float*)d_in[0];
    const float* pair  = (const float*)d_in[1];
    const float* W1n   = (const float*)d_in[2];
    const float* W1p   = (const float*)d_in[3];
    const float* b1    = (const float*)d_in[4];
    const float* W2    = (const float*)d_in[5];
    const float* b2    = (const float*)d_in[6];
    const float* W3    = (const float*)d_in[7];
    const float* b3    = (const float*)d_in[8];
    const float* scale = (const float*)d_in[9];
    const float* bias  = (const float*)d_in[10];
    float* out = (float*)d_out;

    float* hp = (float*)d_ws;                                   // 3200*512 f32
    float* hnb = hp + (size_t)BB*NJK*HID;                       // 80*512 f32
    unsigned short* w2f = (unsigned short*)(hnb + BB*NN*HID);   // 512*512 bf16

    hipLaunchKernelGGL(prep_kernel, dim3(426), dim3(256), 0, stream,
                       node, pair, W1n, W1p, b1, W2, hp, hnb, w2f);
    hipLaunchKernelGGL(main_kernel, dim3(1000), dim3(512), 0, stream,
                       hp, hnb, w2f, b2, W3, b3, scale, bias, out);
}